// Round 1
// 445.650 us; speedup vs baseline: 1.0300x; 1.0300x over previous
//
#include <hip/hip_runtime.h>
#include <hip/hip_bf16.h>
#include <stdint.h>

#define HD 768
#define BB 4
#define TT 4096
#define NT (BB*TT)      /* 16384 tokens */
#define IM 3072
#define NCH 128
#define CHL (TT/NCH)    /* 32 */
#define MCH 4           /* MLP token chunks (small-ws fallback) */
#define MCT (NT/MCH)    /* 4096 tokens per MLP chunk */

typedef int v4i __attribute__((ext_vector_type(4)));
typedef __hip_bfloat16 bf16;
typedef unsigned int uint32;

__device__ __forceinline__ float wave_sum(float v){
#pragma unroll
  for (int o=32;o;o>>=1) v += __shfl_down(v,o);
  return v;
}
__device__ __forceinline__ float wave_sum_x(float v){
#pragma unroll
  for (int o=32;o;o>>=1) v += __shfl_xor(v,o);
  return v;
}
__device__ __forceinline__ float wave_max_x(float v){
#pragma unroll
  for (int o=32;o;o>>=1) v = fmaxf(v,__shfl_xor(v,o));
  return v;
}
__device__ __forceinline__ float block_sum(float v, float* lds){
  const int nw = blockDim.x >> 6;
  v = wave_sum(v);
  if ((threadIdx.x&63)==0) lds[threadIdx.x>>6] = v;
  __syncthreads();
  float r = lds[0];
  for (int i=1;i<nw;++i) r += lds[i];
  __syncthreads();
  return r;
}
__device__ __forceinline__ float sigmoidf_(float x){ return __builtin_amdgcn_rcpf(1.f + __expf(-x)); }
__device__ __forceinline__ float siluf_(float x){ return x * __builtin_amdgcn_rcpf(1.f + __expf(-x)); }
__device__ __forceinline__ float b2f(bf16 v){ return __bfloat162float(v); }
__device__ __forceinline__ bf16  f2b(float v){ return __float2bfloat16(v); }
__device__ __forceinline__ float bfb2f(uint32 u16){ uint32 v = u16<<16; return __builtin_bit_cast(float, v); }
__device__ __forceinline__ uint16_t packq2(float q0, float q1){
  int a = (int)q0, b = (int)q1;
  return (uint16_t)((a&0xff) | ((b&0xff)<<8));
}
__device__ __forceinline__ uint32 packq4(float a, float b, float c, float d){
  return (uint32)((int)a&0xff) | (((uint32)((int)b&0xff))<<8) |
         (((uint32)((int)c&0xff))<<16) | (((uint32)((int)d&0xff))<<24);
}
__device__ __forceinline__ uint32 pack2bf(float a, float b){
  uint32 ua = __builtin_bit_cast(uint16_t, f2b(a));
  uint32 ub = __builtin_bit_cast(uint16_t, f2b(b));
  return ua | (ub<<16);
}
__device__ __forceinline__ float clampq(float v){ return fminf(fmaxf(v,-128.f),127.f); }
__device__ __forceinline__ void gl_lds16(const int8_t* g, void* l){
  __builtin_amdgcn_global_load_lds((const __attribute__((address_space(1))) void*)g,
                                   (__attribute__((address_space(3))) void*)l, 16, 0, 0);
}

// ---------------- fused weight quantization (3 launches total) ----------------
struct WArgs { const float* p[7]; int n[7]; size_t off[7]; };

#define WC1 589824
#define WC2 1179648
#define WC3 1769472
#define WC4 2359296
#define WC5 7077888
#define WC6 9437184
#define WCT 10616832

__global__ __launch_bounds__(256) void absum_part_all(WArgs wa, float* __restrict__ part){
  __shared__ float lds[8];
  const int seg = blockIdx.y;
  const int n4 = wa.n[seg] >> 2;
  const float4* w = (const float4*)wa.p[seg];
  float s = 0.f;
  for (int i = blockIdx.x*256 + threadIdx.x; i < n4; i += gridDim.x*256){
    float4 v = w[i];
    s += (fabsf(v.x)+fabsf(v.y)) + (fabsf(v.z)+fabsf(v.w));
  }
  s = block_sum(s, lds);
  if (threadIdx.x==0) part[seg*64 + blockIdx.x] = s;
}
__global__ __launch_bounds__(512) void absum_final_all(const float* __restrict__ part, WArgs wa,
                                                       float* __restrict__ wscv, float* __restrict__ wrec){
  int seg = threadIdx.x >> 6, lane = threadIdx.x & 63;
  float v = (seg < 7) ? part[seg*64 + lane] : 0.f;
  v = wave_sum(v);
  if (seg < 7 && lane == 0){
    float m = fmaxf(v / (float)wa.n[seg], 1e-5f);
    wscv[seg] = m; wrec[seg] = 1.f/m;
  }
}
__global__ __launch_bounds__(256) void wquant_all(WArgs wa, const float* __restrict__ wrec,
                                                  int8_t* __restrict__ q){
  const int seg = blockIdx.y;
  const int n4 = wa.n[seg] >> 2;
  const float4* p = (const float4*)wa.p[seg];
  uint32* qo = (uint32*)(q + wa.off[seg]);
  const float rc = wrec[seg];
  for (int i = blockIdx.x*256 + threadIdx.x; i < n4; i += gridDim.x*256){
    float4 v = p[i];
    int a  = (int)fminf(fmaxf(rintf(v.x*rc),-1.f),1.f);
    int b  = (int)fminf(fmaxf(rintf(v.y*rc),-1.f),1.f);
    int cc = (int)fminf(fmaxf(rintf(v.z*rc),-1.f),1.f);
    int d  = (int)fminf(fmaxf(rintf(v.w*rc),-1.f),1.f);
    qo[i] = (uint32)(a&0xff) | ((uint32)(b&0xff)<<8) | ((uint32)(cc&0xff)<<16) | ((uint32)(d&0xff)<<24);
  }
}

// ---------------- AdaLN embedding (tiny) ----------------
__global__ __launch_bounds__(256) void ada_emb(const float* __restrict__ c, const float* __restrict__ w_emb,
                                               const float* __restrict__ b_emb,
                                               float* __restrict__ scaleA, float* __restrict__ gateA){
  int o = blockIdx.x*4 + (threadIdx.x>>6);   // 0..6143
  int lane = threadIdx.x & 63;
  int b = o / 1536, n = o % 1536;
  const float* cr = c + b*HD;
  const float* wr = w_emb + (size_t)n*HD;
  float s = 0.f;
  for (int k=lane; k<HD; k+=64){
    float cv = cr[k];
    s += siluf_(cv)*wr[k];
  }
  s = wave_sum(s);
  if (lane==0){
    s += b_emb[n];
    if (n < HD) scaleA[b*HD+n] = s;
    else        gateA[b*HD+(n-HD)] = s;
  }
}

// ---------------- LN * (1+scale) -> rms_norm -> int8 quant (wave per token) ----------------
__global__ __launch_bounds__(256) void ln_quant(const float* __restrict__ x, const float* __restrict__ scaleA,
                                                int8_t* __restrict__ xq, float* __restrict__ rsx){
  const int tok  = blockIdx.x*4 + (threadIdx.x>>6);
  const int lane = threadIdx.x & 63;
  const int b = tok >> 12;                    // T=4096
  const float4* xr = (const float4*)(x + (size_t)tok*HD);
  const float4* sr = (const float4*)(scaleA + (size_t)b*HD);
  float4 v[3];
  float s1 = 0.f, s2 = 0.f;
#pragma unroll
  for (int j=0;j<3;++j){
    v[j] = xr[lane + j*64];
    s1 += (v[j].x+v[j].y)+(v[j].z+v[j].w);
    s2 += (v[j].x*v[j].x+v[j].y*v[j].y)+(v[j].z*v[j].z+v[j].w*v[j].w);
  }
  s1 = wave_sum_x(s1); s2 = wave_sum_x(s2);
  const float mu  = s1 * (1.f/768.f);
  const float var = fmaxf(s2 * (1.f/768.f) - mu*mu, 0.f);
  const float r1  = rsqrtf(var + 1e-6f);
  float sv[12]; float ms = 0.f, amr = 0.f;
#pragma unroll
  for (int j=0;j<3;++j){
    float4 sc = sr[lane + j*64];
    float a0 = (v[j].x-mu)*r1*(1.f+sc.x);
    float a1 = (v[j].y-mu)*r1*(1.f+sc.y);
    float a2 = (v[j].z-mu)*r1*(1.f+sc.z);
    float a3 = (v[j].w-mu)*r1*(1.f+sc.w);
    sv[4*j]=a0; sv[4*j+1]=a1; sv[4*j+2]=a2; sv[4*j+3]=a3;
    ms += (a0*a0+a1*a1)+(a2*a2+a3*a3);
    amr = fmaxf(amr, fmaxf(fmaxf(fabsf(a0),fabsf(a1)),fmaxf(fabsf(a2),fabsf(a3))));
  }
  ms = wave_sum_x(ms); amr = wave_max_x(amr);
  const float r2 = rsqrtf(ms*(1.f/768.f) + 1e-6f);
  const float am = fmaxf(amr*r2, 1e-5f);
  const float sx = 127.f/am;
  uint32* qo = (uint32*)(xq + (size_t)tok*HD);
#pragma unroll
  for (int j=0;j<3;++j){
    qo[lane + j*64] = packq4(clampq(rintf(sv[4*j]*r2*sx)),   clampq(rintf(sv[4*j+1]*r2*sx)),
                             clampq(rintf(sv[4*j+2]*r2*sx)), clampq(rintf(sv[4*j+3]*r2*sx)));
  }
  if (lane==0) rsx[tok] = am*(1.f/127.f);
}

// ---------------- generic rms_norm -> int8 quant (wave per token, C u32/lane) ----------------
template<int C>
__global__ __launch_bounds__(256) void rms_quant_w(const uint32* __restrict__ zin, int8_t* __restrict__ q,
                                                   float* __restrict__ rs){
  const int tok  = blockIdx.x*4 + (threadIdx.x>>6);
  const int lane = threadIdx.x & 63;
  const uint32* zp = zin + (size_t)tok*C*64;
  uint32 u[C]; float ss = 0.f, amr = 0.f;
#pragma unroll
  for (int j=0;j<C;++j){
    u[j] = zp[lane + j*64];
    float a = bfb2f(u[j] & 0xffff), b = bfb2f(u[j] >> 16);
    ss += a*a + b*b;
    amr = fmaxf(amr, fmaxf(fabsf(a),fabsf(b)));
  }
  ss = wave_sum_x(ss); amr = wave_max_x(amr);
  const float r = rsqrtf(ss*(1.f/(float)(C*128)) + 1e-6f);
  const float am = fmaxf(amr*r, 1e-5f);
  const float sx = 127.f/am;
  uint16_t* qo = (uint16_t*)(q + (size_t)tok*C*128);
#pragma unroll
  for (int j=0;j<C;++j){
    float a = bfb2f(u[j] & 0xffff), b = bfb2f(u[j] >> 16);
    qo[lane + j*64] = packq2(clampq(rintf(a*r*sx)), clampq(rintf(b*r*sx)));
  }
  if (lane==0) rs[tok] = am*(1.f/127.f);
}

// ---- rms_norm -> int8 quant over CONCAT of two 768-ch bf16 buffers (big-ws path) ----
__global__ __launch_bounds__(256) void rms_quant_cat(const uint32* __restrict__ pa, const uint32* __restrict__ pb,
                                                     int8_t* __restrict__ q, float* __restrict__ rs){
  const int tok  = blockIdx.x*4 + (threadIdx.x>>6);
  const int lane = threadIdx.x & 63;
  const uint32* ap = pa + (size_t)tok*(HD/2);
  const uint32* bp = pb + (size_t)tok*(HD/2);
  uint32 u[12]; float ss = 0.f, amr = 0.f;
#pragma unroll
  for (int j=0;j<6;++j){
    u[j] = ap[lane + j*64];
    float a = bfb2f(u[j] & 0xffff), b = bfb2f(u[j] >> 16);
    ss += a*a + b*b;
    amr = fmaxf(amr, fmaxf(fabsf(a),fabsf(b)));
  }
#pragma unroll
  for (int j=0;j<6;++j){
    u[6+j] = bp[lane + j*64];
    float a = bfb2f(u[6+j] & 0xffff), b = bfb2f(u[6+j] >> 16);
    ss += a*a + b*b;
    amr = fmaxf(amr, fmaxf(fabsf(a),fabsf(b)));
  }
  ss = wave_sum_x(ss); amr = wave_max_x(amr);
  const float r = rsqrtf(ss*(1.f/1536.f) + 1e-6f);
  const float am = fmaxf(amr*r, 1e-5f);
  const float sx = 127.f/am;
  uint16_t* qo = (uint16_t*)(q + (size_t)tok*(2*HD));
#pragma unroll
  for (int j=0;j<6;++j){
    float a = bfb2f(u[j] & 0xffff), b = bfb2f(u[j] >> 16);
    qo[lane + j*64] = packq2(clampq(rintf(a*r*sx)), clampq(rintf(b*r*sx)));
  }
#pragma unroll
  for (int j=0;j<6;++j){
    float a = bfb2f(u[6+j] & 0xffff), b = bfb2f(u[6+j] >> 16);
    qo[384 + lane + j*64] = packq2(clampq(rintf(a*r*sx)), clampq(rintf(b*r*sx)));
  }
  if (lane==0) rs[tok] = am*(1.f/127.f);
}

// ---------------- rms_norm(o)*w_gn*silu(g) -> rms_norm -> quant (wave per token) ----------------
__global__ __launch_bounds__(256) void gate_norm_quant(const uint32* __restrict__ o, const uint32* __restrict__ gs,
                                                       const float* __restrict__ w_gn,
                                                       int8_t* __restrict__ oq, float* __restrict__ rso){
  const int tok  = blockIdx.x*4 + (threadIdx.x>>6);
  const int lane = threadIdx.x & 63;
  const uint32* op = o  + (size_t)tok*(HD/2);
  const uint32* gp = gs + (size_t)tok*(HD/2);
  const float2* wg = (const float2*)w_gn;
  uint32 u[6]; float ms = 0.f;
#pragma unroll
  for (int j=0;j<6;++j){
    u[j] = op[lane + j*64];
    float a = bfb2f(u[j] & 0xffff), b = bfb2f(u[j] >> 16);
    ms += a*a + b*b;
  }
  ms = wave_sum_x(ms);
  const float rn = rsqrtf(ms*(1.f/768.f) + 1e-6f);
  float uu[12]; float ms2 = 0.f, amr = 0.f;
#pragma unroll
  for (int j=0;j<6;++j){
    uint32 g = gp[lane + j*64];
    float2 w = wg[lane + j*64];
    float a = bfb2f(u[j] & 0xffff)*rn*w.x*bfb2f(g & 0xffff);
    float b = bfb2f(u[j] >> 16)  *rn*w.y*bfb2f(g >> 16);
    uu[2*j]=a; uu[2*j+1]=b;
    ms2 += a*a + b*b;
    amr = fmaxf(amr, fmaxf(fabsf(a),fabsf(b)));
  }
  ms2 = wave_sum_x(ms2); amr = wave_max_x(amr);
  const float r2 = rsqrtf(ms2*(1.f/768.f) + 1e-6f);
  const float am = fmaxf(amr*r2, 1e-5f);
  const float sx = 127.f/am;
  uint16_t* qo = (uint16_t*)(oq + (size_t)tok*HD);
#pragma unroll
  for (int j=0;j<6;++j){
    qo[lane + j*64] = packq2(clampq(rintf(uu[2*j]*r2*sx)), clampq(rintf(uu[2*j+1]*r2*sx)));
  }
  if (lane==0) rso[tok] = am*(1.f/127.f);
}

// ---------------- chunked linear-recurrence scan (384 thr, 2 ch/thr) ----------------
__global__ __launch_bounds__(384) void scan_pass1(const uint32* __restrict__ iact, const uint32* __restrict__ fsig,
                                                  float* __restrict__ chF, float* __restrict__ chH){
  const int blk = blockIdx.x;                 // b*NCH + chunk
  const int b = blk >> 7, ch = blk & (NCH-1);
  const int t0 = b*TT + ch*CHL;
  const size_t base = (size_t)t0*(HD/2) + threadIdx.x;
  float F0=1.f,F1=1.f,h0=0.f,h1=0.f;
#pragma unroll 4
  for (int s=0;s<CHL;++s){
    uint32 fu = fsig[base + (size_t)s*(HD/2)];
    uint32 iu = iact[base + (size_t)s*(HD/2)];
    float f0 = bfb2f(fu&0xffff), f1 = bfb2f(fu>>16);
    float a0 = bfb2f(iu&0xffff), a1 = bfb2f(iu>>16);
    h0 = f0*h0 + a0; h1 = f1*h1 + a1;
    F0 *= f0; F1 *= f1;
  }
  size_t cb = (size_t)blk*HD + 2*threadIdx.x;
  *(float2*)(chF + cb) = make_float2(F0,F1);
  *(float2*)(chH + cb) = make_float2(h0,h1);
}
__global__ __launch_bounds__(256) void scan_combine(float* __restrict__ chF, float* __restrict__ chH){
  const int gid = blockIdx.x*256 + threadIdx.x;   // 0..3071
  const int b = gid / HD, d = gid % HD;
  float h = 0.f;
#pragma unroll 8
  for (int c=0;c<NCH;++c){
    size_t idx = (size_t)(b*NCH+c)*HD + d;
    float F = chF[idx], Hl = chH[idx];
    chH[idx] = h;                 // h_in for chunk c
    h = F*h + Hl;
  }
}
__global__ __launch_bounds__(384) void scan_pass2(const uint32* iact, const uint32* __restrict__ fsig,
                                                  const float* __restrict__ chH, uint32* o){
  const int blk = blockIdx.x;
  const int b = blk >> 7, ch = blk & (NCH-1);
  const int t0 = b*TT + ch*CHL;
  const size_t base = (size_t)t0*(HD/2) + threadIdx.x;
  float2 hin = *(const float2*)(chH + (size_t)blk*HD + 2*threadIdx.x);
  float h0 = hin.x, h1 = hin.y;
#pragma unroll 4
  for (int s=0;s<CHL;++s){
    uint32 fu = fsig[base + (size_t)s*(HD/2)];
    uint32 iu = iact[base + (size_t)s*(HD/2)];
    float f0 = bfb2f(fu&0xffff), f1 = bfb2f(fu>>16);
    float a0 = bfb2f(iu&0xffff), a1 = bfb2f(iu>>16);
    h0 = f0*h0 + a0; h1 = f1*h1 + a1;
    uint16_t pa = __builtin_bit_cast(uint16_t, f2b(h0));
    uint16_t pb = __builtin_bit_cast(uint16_t, f2b(h1));
    o[base + (size_t)s*(HD/2)] = (uint32)pa | ((uint32)pb<<16);  // o aliases iact: value dep guarantees order
  }
}

// ------- i8 MFMA GEMM: 256x128 block tile (8 waves), LDS dbuf, global_load_lds -------
// mfma(B,A): lane&15 = token, (lane>>4)*4+reg = channel -> packed 8B/16B stores.
// Per wave: 64 tokens x 64 channels (x dual). Wave grid 4(m) x 2(n).
// K-loop: counted-vmcnt 2-ahead pipeline (T3+T4): loads for tile t+2 issued at t,
// never drain vmcnt to 0 in steady state; raw s_barrier pairs instead of __syncthreads.
enum { EPI_IF=0, EPI_SILU=1, EPI_STORE=2, EPI_SWIGLU=3, EPI_PROJ=4 };

template<int EPI, bool DUAL>
__global__ __launch_bounds__(512) void gemm_i8(
    const int8_t* __restrict__ A, const float* __restrict__ rsA,
    const int8_t* __restrict__ B0, const int8_t* __restrict__ B1,
    const float* __restrict__ ws0p, const float* __restrict__ ws1p,
    int K, void* __restrict__ out0v, void* __restrict__ out1v,
    int ldOut, int colOff,
    const float* __restrict__ bias, const float* __restrict__ gateA,
    const float* __restrict__ xres)
{
  __shared__ __align__(16) uint8_t sA [2][16384];
  __shared__ __align__(16) uint8_t sB0[2][8192];
  __shared__ __align__(16) uint8_t sB1[DUAL?2:1][8192];

  const int lane = threadIdx.x & 63;
  const int wv   = threadIdx.x >> 6;       // 0..7
  const int m0 = blockIdx.x*256;
  const int n0 = blockIdx.y*128;
  const int wm = (wv>>1)*64;               // 0,64,128,192
  const int wn = (wv&1)*64;                // 0,64
  const int lr = lane & 15;
  const int sl = lane >> 4;                // 16B slot 0..3

  // staging: A = 16 chunks of 1024B (2/wave), B0 = 8 chunks (1/wave), B1 = 8 chunks (1/wave)
  const int8_t* gA[2]; const int8_t* gB0; const int8_t* gB1;
  int ldsOffA[2], ldsOffB;
#pragma unroll
  for (int j=0;j<2;++j){
    int q = wv*2 + j;                      // 0..15
    int r = q*16 + (lane>>2);              // 0..255
    int cg = (lane&3) ^ ((r>>1)&3);        // inverse-swizzled source slot
    gA[j] = A + (size_t)(m0+r)*K + cg*16;
    ldsOffA[j] = q*1024;
  }
  {
    int r = wv*16 + (lane>>2);             // 0..127
    int cg = (lane&3) ^ ((r>>1)&3);
    gB0 = B0 + (size_t)(n0+r)*K + cg*16;
    gB1 = DUAL ? (B1 + (size_t)(n0+r)*K + cg*16) : (const int8_t*)0;
    ldsOffB = wv*1024;
  }
  // fragment ds_read byte offsets (swizzled)
  int offA[4], offB[4];
#pragma unroll
  for (int i=0;i<4;++i){
    int Ra = wm + i*16 + lr;               // 0..255
    offA[i] = Ra*64 + ((sl ^ ((Ra>>1)&3))<<4);
    int Rb = wn + i*16 + lr;               // 0..127
    offB[i] = Rb*64 + ((sl ^ ((Rb>>1)&3))<<4);
  }

  v4i acc0[4][4], acc1[4][4];
  const v4i vzero = {0,0,0,0};
#pragma unroll
  for (int i=0;i<4;++i)
#pragma unroll
    for (int j=0;j<4;++j){ acc0[i][j]=vzero; acc1[i][j]=vzero; }

  const int NTI = K >> 6;
  // prologue: stage tiles 0 and 1 (both buffers)
#pragma unroll
  for (int j=0;j<2;++j) gl_lds16(gA[j], &sA[0][ldsOffA[j]]);
  gl_lds16(gB0, &sB0[0][ldsOffB]);
  if (DUAL) gl_lds16(gB1, &sB1[0][ldsOffB]);
#pragma unroll
  for (int j=0;j<2;++j) gl_lds16(gA[j]+64, &sA[1][ldsOffA[j]]);
  gl_lds16(gB0+64, &sB0[1][ldsOffB]);
  if (DUAL) gl_lds16(gB1+64, &sB1[1][ldsOffB]);

  int cur = 0;
  for (int t=0; t<NTI; ++t){
    // wait until MY loads for tile t have landed; leave tile t+1's in flight.
    if (t+1 < NTI){
      if constexpr (DUAL) asm volatile("s_waitcnt vmcnt(4)" ::: "memory");
      else                asm volatile("s_waitcnt vmcnt(3)" ::: "memory");
    } else {
      asm volatile("s_waitcnt vmcnt(0)" ::: "memory");
    }
    asm volatile("s_barrier" ::: "memory");   // everyone's tile-t data is in LDS

    v4i av[4], b0v[4], b1v[4];
#pragma unroll
    for (int i=0;i<4;++i){
      av[i]  = *(const v4i*)&sA [cur][offA[i]];
      b0v[i] = *(const v4i*)&sB0[cur][offB[i]];
    }
    if constexpr (DUAL){
#pragma unroll
      for (int i=0;i<4;++i) b1v[i] = *(const v4i*)&sB1[cur][offB[i]];
    }
    asm volatile("s_waitcnt lgkmcnt(0)" ::: "memory");  // my ds_reads complete
    asm volatile("s_barrier" ::: "memory");   // all waves done reading buf[cur]

    // issue loads for tile t+2 into the buffer we just consumed
    if (t+2 < NTI){
      const int ko = (t+2)*64;
#pragma unroll
      for (int j=0;j<2;++j) gl_lds16(gA[j]+ko, &sA[cur][ldsOffA[j]]);
      gl_lds16(gB0+ko, &sB0[cur][ldsOffB]);
      if (DUAL) gl_lds16(gB1+ko, &sB1[cur][ldsOffB]);
    }
    __builtin_amdgcn_sched_barrier(0);        // pin load-issue before the MFMA cluster

    __builtin_amdgcn_s_setprio(1);
#pragma unroll
    for (int mi=0;mi<4;++mi){
#pragma unroll
      for (int ni=0;ni<4;++ni){
        acc0[mi][ni] = __builtin_amdgcn_mfma_i32_16x16x64_i8(b0v[ni], av[mi], acc0[mi][ni], 0,0,0);
        if constexpr (DUAL)
          acc1[mi][ni] = __builtin_amdgcn_mfma_i32_16x16x64_i8(b1v[ni], av[mi], acc1[mi][ni], 0,0,0);
      }
    }
    __builtin_amdgcn_s_setprio(0);
    cur ^= 1;
  }

  const float w0 = *ws0p;
  const float w1 = DUAL ? *ws1p : 0.f;
  const int rb = sl*4;                 // 4 consecutive output channels per thread
  const int em0 = m0 + wm, en0 = n0 + wn;
#pragma unroll
  for (int mi=0;mi<4;++mi){
    const int tok = em0 + mi*16 + lr;
    const float rs = rsA[tok];
#pragma unroll
    for (int ni=0;ni<4;++ni){
      const int ch = en0 + ni*16 + rb;
      float y0[4], y1[4];
#pragma unroll
      for (int r=0;r<4;++r){
        y0[r] = (float)acc0[mi][ni][r] * rs * w0;
        if constexpr (DUAL) y1[r] = (float)acc1[mi][ni][r] * rs * w1;
      }
      if constexpr (EPI==EPI_IF){
        float fs[4], io[4];
#pragma unroll
        for (int r=0;r<4;++r){ fs[r] = sigmoidf_(y1[r]); io[r] = siluf_(y0[r])*(1.f-fs[r]); }
        uint2 ui, uf;
        ui.x = pack2bf(io[0],io[1]); ui.y = pack2bf(io[2],io[3]);
        uf.x = pack2bf(fs[0],fs[1]); uf.y = pack2bf(fs[2],fs[3]);
        *(uint2*)((bf16*)out0v + (size_t)tok*ldOut + ch) = ui;
        *(uint2*)((bf16*)out1v + (size_t)tok*ldOut + ch) = uf;
      } else if constexpr (EPI==EPI_SILU){
        uint2 u;
        u.x = pack2bf(siluf_(y0[0]), siluf_(y0[1]));
        u.y = pack2bf(siluf_(y0[2]), siluf_(y0[3]));
        *(uint2*)((bf16*)out0v + (size_t)tok*ldOut + ch) = u;
      } else if constexpr (EPI==EPI_STORE){
        uint2 u;
        u.x = pack2bf(y0[0],y0[1]); u.y = pack2bf(y0[2],y0[3]);
        *(uint2*)((bf16*)out0v + (size_t)tok*ldOut + colOff + ch) = u;
      } else if constexpr (EPI==EPI_SWIGLU){
        uint2 u;
        u.x = pack2bf(siluf_(y0[0])*y1[0], siluf_(y0[1])*y1[1]);
        u.y = pack2bf(siluf_(y0[2])*y1[2], siluf_(y0[3])*y1[3]);
        *(uint2*)((bf16*)out0v + (size_t)tok*ldOut + ch) = u;
      } else { // EPI_PROJ
        const int bidx = tok >> 12;
        float4 b4 = *(const float4*)(bias + ch);
        float4 g4 = *(const float4*)(gateA + bidx*HD + ch);
        float4 x4 = *(const float4*)(xres + (size_t)tok*HD + ch);
        float4 o4;
        o4.x = x4.x + g4.x*(y0[0] + b4.x);
        o4.y = x4.y + g4.y*(y0[1] + b4.y);
        o4.z = x4.z + g4.z*(y0[2] + b4.z);
        o4.w = x4.w + g4.w*(y0[3] + b4.w);
        *(float4*)((float*)out0v + (size_t)tok*HD + ch) = o4;
      }
    }
  }
}

// ---------------- host ----------------
extern "C" void kernel_launch(void* const* d_in, const int* in_sizes, int n_in,
                              void* d_out, int out_size, void* d_ws, size_t ws_size,
                              hipStream_t stream){
  const float* x      = (const float*)d_in[0];
  const float* c      = (const float*)d_in[1];
  const float* w_emb  = (const float*)d_in[2];
  const float* b_emb  = (const float*)d_in[3];
  const float* w_i    = (const float*)d_in[4];
  const float* w_f    = (const float*)d_in[5];
  const float* w_g    = (const float*)d_in[6];
  const float* w_gn   = (const float*)d_in[7];
  const float* w_o    = (const float*)d_in[8];
  const float* w_gate = (const float*)d_in[9];
  const float* w_down = (const float*)d_in[10];
  const float* w_proj = (const float*)d_in[11];
  const float* b_proj = (const float*)d_in[12];
  float* out = (float*)d_out;
  char* ws = (char*)d_ws;

  // ---- common prefix layout ----
  constexpr size_t SZ_HH   = (size_t)HD*HD;
  constexpr size_t o_wq     = 0;
  constexpr size_t o_wsc    = o_wq + (size_t)WCT;
  constexpr size_t o_wrecip = o_wsc    + 256;
  constexpr size_t o_part   = o_wrecip + 256;
  constexpr size_t o_scaleA = o_part   + 2048;
  constexpr size_t o_gateA  = o_scaleA + (size_t)BB*HD*4;
  constexpr size_t o_rsx    = o_gateA  + (size_t)BB*HD*4;
  constexpr size_t o_rso    = o_rsx    + (size_t)NT*4;
  constexpr size_t o_rsh    = o_rso    + (size_t)NT*4;
  constexpr size_t o_rsm    = o_rsh    + (size_t)NT*4;
  constexpr size_t o_xq     = o_rsm    + (size_t)NT*4;
  constexpr size_t o_END0   = o_xq     + (size_t)NT*HD;      // ~23.5 MB

  // small path regions (round-7 layout)
  constexpr size_t o_R1     = o_END0;
  constexpr size_t o_R2     = o_R1     + (size_t)NT*HD*2;
  constexpr size_t o_R3     = o_R2     + (size_t)NT*HD*2;
  constexpr size_t o_chF    = o_R3     + (size_t)NT*HD*2;
  constexpr size_t o_chH    = o_chF    + (size_t)BB*NCH*HD*4;
  constexpr size_t o_R4     = o_chH    + (size_t)BB*NCH*HD*4;
  constexpr size_t NEED_S   = o_R4     + (size_t)NT*HD;      // ~113 MB

  // big path regions
  constexpr size_t o_Z      = o_END0;                        // 100 MB
  constexpr size_t o_M      = o_Z + (size_t)NT*IM*2;         // 50 MB
  constexpr size_t o_chF2   = o_M + (size_t)NT*IM;
  constexpr size_t o_chH2   = o_chF2 + (size_t)BB*NCH*HD*4;
  constexpr size_t NEED_B   = o_chH2 + (size_t)BB*NCH*HD*4;  // ~177.5 MB

  if (ws_size < NEED_S) return;
  const bool big = (ws_size >= NEED_B);

  float*  wscv  = (float*)(ws + o_wsc);
  float*  wrec  = (float*)(ws + o_wrecip);
  float*  part  = (float*)(ws + o_part);
  float*  scaleA= (float*)(ws + o_scaleA);
  float*  gateA = (float*)(ws + o_gateA);
  float*  rsx   = (float*)(ws + o_rsx);
  float*  rso   = (float*)(ws + o_rso);
  float*  rsh   = (float*)(ws + o_rsh);
  float*  rsm   = (float*)(ws + o_rsm);
  int8_t* xq    = (int8_t*)(ws + o_xq);
  int8_t* wqall = (int8_t*)(ws + o_wq);
  int8_t* wqp[7] = { wqall, wqall+WC1, wqall+WC2, wqall+WC3, wqall+WC4, wqall+WC5, wqall+WC6 };

  WArgs wa;
  wa.p[0]=w_i; wa.p[1]=w_f; wa.p[2]=w_g; wa.p[3]=w_o; wa.p[4]=w_gate; wa.p[5]=w_down; wa.p[6]=w_proj;
  wa.n[0]=(int)SZ_HH; wa.n[1]=(int)SZ_HH; wa.n[2]=(int)SZ_HH; wa.n[3]=(int)SZ_HH;
  wa.n[4]=2*IM*HD; wa.n[5]=HD*IM; wa.n[6]=HD*2*HD;
  wa.off[0]=0; wa.off[1]=WC1; wa.off[2]=WC2; wa.off[3]=WC3; wa.off[4]=WC4; wa.off[5]=WC5; wa.off[6]=WC6;

  // 1) weight quantization + AdaLN + ln_quant (both paths)
  absum_part_all <<<dim3(64,7),  dim3(256), 0, stream>>>(wa, part);
  absum_final_all<<<dim3(1),     dim3(512), 0, stream>>>(part, wa, wscv, wrec);
  wquant_all     <<<dim3(256,7), dim3(256), 0, stream>>>(wa, wrec, wqall);
  ada_emb <<<dim3(1536), dim3(256), 0, stream>>>(c, w_emb, b_emb, scaleA, gateA);
  ln_quant<<<dim3(NT/4), dim3(256), 0, stream>>>(x, scaleA, xq, rsx);

  if (big){
    // ---- big-ws path: un-chunked MLP first ----
    bf16* zc      = (bf16*)(ws + o_Z);                        // [NT, IM]
    bf16* iact    = (bf16*)(ws + o_Z);                        // later (zc dead)
    bf16* fsig    = (bf16*)(ws + o_Z + (size_t)NT*HD*2);
    bf16* gsilu   = (bf16*)(ws + o_Z + (size_t)2*NT*HD*2);
    bf16* attn    = gsilu;
    bf16* mlp     = (bf16*)(ws + o_Z + (size_t)3*NT*HD*2);
    int8_t* mq    = (int8_t*)(ws + o_M);
    int8_t* oq    = (int8_t*)(ws + o_M);                      // after mq dead
    int8_t* hq    = (int8_t*)(ws + o_M + (size_t)NT*HD);
    float* chF    = (float*)(ws + o_chF2);
    float* chH    = (float*)(ws + o_chH2);
    bf16* obuf    = iact;

    // MLP: SWiGLU (full) -> rms+quant -> down -> mlp
    gemm_i8<EPI_SWIGLU,true><<<dim3(NT/256,24), dim3(512), 0, stream>>>(
        xq, rsx, wqp[4], wqp[4] + (size_t)IM*HD, wscv+4, wscv+4, HD,
        zc, nullptr, IM, 0, nullptr, nullptr, nullptr);
    rms_quant_w<24><<<dim3(NT/4), dim3(256), 0, stream>>>((const uint32*)zc, mq, rsm);
    gemm_i8<EPI_STORE,false><<<dim3(NT/256,6), dim3(512), 0, stream>>>(
        mq, rsm, wqp[5], nullptr, wscv+5, nullptr, IM, mlp, nullptr, HD, 0, nullptr, nullptr, nullptr);

    // attention path (zc dead; iact/fsig/gsilu overlay it)
    gemm_i8<EPI_IF,true><<<dim3(NT/256,6), dim3(512), 0, stream>>>(
        xq, rsx, wqp[0], wqp[1], wscv+0, wscv+1, HD, iact, fsig, HD, 0, nullptr, nullptr, nullptr);
    gemm_i8<EPI_SILU,false><<<dim3(NT/256,6), dim3(512), 0, stream>>>(
        xq, rsx, wqp[2], nullptr, wscv+2, nullptr, HD, gsilu, nullptr, HD, 0, nullptr, nullptr, nullptr);
    scan_pass1 <<<dim3(BB*NCH), dim3(384), 0, stream>>>((const uint32*)iact, (const uint32*)fsig, chF, chH);
    scan_combine<<<dim3(12),    dim3(256), 0, stream>>>(chF, chH);
    scan_pass2 <<<dim3(BB*NCH), dim3(384), 0, stream>>>((const uint32*)iact, (const uint32*)fsig, chH, (uint32*)obuf);
    gate_norm_quant<<<dim3(NT/4), dim3(256), 0, stream>>>((const uint32*)obuf, (const uint32*)gsilu, w_gn, oq, rso);
    gemm_i8<EPI_STORE,false><<<dim3(NT/256,6), dim3(512), 0, stream>>>(
        oq, rso, wqp[3], nullptr, wscv+3, nullptr, HD, attn, nullptr, HD, 0, nullptr, nullptr, nullptr);

    // concat-quant + final projection
    rms_quant_cat<<<dim3(NT/4), dim3(256), 0, stream>>>((const uint32*)attn, (const uint32*)mlp, hq, rsh);
    gemm_i8<EPI_PROJ,false><<<dim3(NT/256,6), dim3(512), 0, stream>>>(
        hq, rsh, wqp[6], nullptr, wscv+6, nullptr, 2*HD, out, nullptr, HD, 0, b_proj, gateA, x);
  } else {
    // ---- small-ws fallback ----
    bf16*   iact  = (bf16*)(ws + o_R1);
    bf16*   fsig  = (bf16*)(ws + o_R2);
    bf16*   gsilu = (bf16*)(ws + o_R3);
    bf16*   obuf  = iact;
    bf16*   hs    = (bf16*)(ws + o_R1);
    bf16*   zc    = (bf16*)(ws + o_R3);
    int8_t* hq    = (int8_t*)(ws + o_R3);
    float*  chF   = (float*)(ws + o_chF);
    float*  chH   = (float*)(ws + o_chH);
    int8_t* oq    = (int8_t*)(ws + o_R4);
    int8_t* mq    = (int8_t*)(ws + o_R4);

    gemm_i8<EPI_IF,true><<<dim3(NT/256,6), dim3(512), 0, stream>>>(
        xq, rsx, wqp[0], wqp[1], wscv+0, wscv+1, HD, iact, fsig, HD, 0, nullptr, nullptr, nullptr);
    gemm_i8<EPI_SILU,false><<<dim3(NT/256,6), dim3(512), 0, stream>>>(
        xq, rsx, wqp[2], nullptr, wscv+2, nullptr, HD, gsilu, nullptr, HD, 0, nullptr, nullptr, nullptr);
    scan_pass1 <<<dim3(BB*NCH), dim3(384), 0, stream>>>((const uint32*)iact, (const uint32*)fsig, chF, chH);
    scan_combine<<<dim3(12),    dim3(256), 0, stream>>>(chF, chH);
    scan_pass2 <<<dim3(BB*NCH), dim3(384), 0, stream>>>((const uint32*)iact, (const uint32*)fsig, chH, (uint32*)obuf);
    gate_norm_quant<<<dim3(NT/4), dim3(256), 0, stream>>>((const uint32*)obuf, (const uint32*)gsilu, w_gn, oq, rso);
    gemm_i8<EPI_STORE,false><<<dim3(NT/256,6), dim3(512), 0, stream>>>(
        oq, rso, wqp[3], nullptr, wscv+3, nullptr, HD, hs, nullptr, 2*HD, 0, nullptr, nullptr, nullptr);
    for (int cc=0; cc<MCH; ++cc){
      const size_t r0 = (size_t)cc*MCT;
      gemm_i8<EPI_SWIGLU,true><<<dim3(MCT/256,24), dim3(512), 0, stream>>>(
          xq + r0*HD, rsx + r0, wqp[4], wqp[4] + (size_t)IM*HD, wscv+4, wscv+4, HD,
          zc, nullptr, IM, 0, nullptr, nullptr, nullptr);
      rms_quant_w<24><<<dim3(MCT/4), dim3(256), 0, stream>>>((const uint32*)zc, mq, rsm);
      gemm_i8<EPI_STORE,false><<<dim3(MCT/256,6), dim3(512), 0, stream>>>(
          mq, rsm, wqp[5], nullptr, wscv+5, nullptr, IM,
          hs + r0*2*HD, nullptr, 2*HD, HD, nullptr, nullptr, nullptr);
    }
    rms_quant_w<12><<<dim3(NT/4), dim3(256), 0, stream>>>((const uint32*)hs, hq, rsh);
    gemm_i8<EPI_PROJ,false><<<dim3(NT/256,6), dim3(512), 0, stream>>>(
        hq, rsh, wqp[6], nullptr, wscv+6, nullptr, 2*HD, out, nullptr, HD, 0, b_proj, gateA, x);
  }

  (void)in_sizes; (void)n_in; (void)out_size;
}